// Round 4
// baseline (30389.380 us; speedup 1.0000x reference)
//
#include <hip/hip_runtime.h>

#define EPSN 1e-6f

// conv1: out[row][d] = sum_c x[row][c]*w1[c][d]; row = ((b*4+h)*4+w) (x flat order)
__global__ void k_conv1(const float* __restrict__ x, const float* __restrict__ w1,
                        float* __restrict__ out) {
  int idx = blockIdx.x * 256 + threadIdx.x;   // 4096*512 total
  int row = idx >> 9, d = idx & 511;
  const float* xr = x + (size_t)row * 1024;
  float s = 0.f;
  for (int c = 0; c < 1024; ++c) s = fmaf(xr[c], w1[c * 512 + d], s);
  out[idx] = s;
}

// instance-norm over the 16 (h,w) positions per (b,d), lrelu, scatter to steps:
// conv1o row = b*16 + h*4 + w ; steps[w][b][h*512+d]  (fp32)
__global__ void k_inorm1(const float* __restrict__ h, const float* __restrict__ gamma,
                         const float* __restrict__ beta, float* __restrict__ steps) {
  int d = blockIdx.y * 256 + threadIdx.x;  // 0..511
  int b = blockIdx.x;                      // 0..255
  float v[16], s = 0.f, s2 = 0.f;
#pragma unroll
  for (int p = 0; p < 16; ++p) {
    float xv = h[((size_t)(b * 16 + p)) * 512 + d];
    v[p] = xv; s += xv; s2 += xv * xv;
  }
  float mean = s * (1.f / 16.f);
  float var = s2 * (1.f / 16.f) - mean * mean;
  float sc = gamma[d] * rsqrtf(var + EPSN);
  float bt = beta[d];
#pragma unroll
  for (int p = 0; p < 16; ++p) {
    int hh = p >> 2, w = p & 3;
    float xn = (v[p] - mean) * sc + bt;
    xn = xn >= 0.f ? xn : 0.2f * xn;
    steps[((size_t)(w * 256 + b)) * 2048 + hh * 512 + d] = xn;
  }
}

// z[b][n] = bias[n] + sum_k xin[b][k]*K[k][n] + sum_k hin[b][k]*R[k][n]
// K,R are the ORIGINAL fp32 [2048][8192] arrays, read directly (coalesced on n).
__global__ void k_cellz(const float* __restrict__ xin, const float* __restrict__ hin,
                        const float* __restrict__ K, const float* __restrict__ R,
                        const float* __restrict__ bias, float* __restrict__ z) {
  int idx = blockIdx.x * 256 + threadIdx.x;   // 256*8192 total
  int b = idx >> 13, n = idx & 8191;
  const float* xr = xin + (size_t)b * 2048;
  const float* hr = hin + (size_t)b * 2048;
  float s = bias[n];
  for (int k = 0; k < 2048; ++k) s = fmaf(xr[k], K[(size_t)k * 8192 + n], s);
  for (int k = 0; k < 2048; ++k) s = fmaf(hr[k], R[(size_t)k * 8192 + n], s);
  z[idx] = s;
}

// all-tanh gates; z already includes bias. c fp32 state in/out, h out fp32.
__global__ void k_gatesf(const float* __restrict__ z, float* __restrict__ c,
                         float* __restrict__ hout) {
  int i = blockIdx.x * 256 + threadIdx.x;  // 256*2048
  int b = i >> 11, u = i & 2047;
  const float* zb = z + (size_t)b * 8192;
  float ig = tanhf(zb[u]);
  float fg = tanhf(zb[u + 2048]);
  float gg = tanhf(zb[u + 4096]);
  float og = tanhf(zb[u + 6144]);
  float cn = fg * c[i] + ig * gg;
  c[i] = cn;
  hout[i] = og * tanhf(cn);
}

// y[b,g,s,d] = ydec[s][b][g*512+d];  z2[row][o] = sum_d y*w2[d][o]; row = b*16+g*4+s
__global__ void k_conv2(const float* __restrict__ ydec, const float* __restrict__ w2,
                        float* __restrict__ z2) {
  int idx = blockIdx.x * 256 + threadIdx.x;   // 4096*1024 total
  int rr = idx >> 10, o = idx & 1023;
  int b = rr >> 4, g = (rr >> 2) & 3, s = rr & 3;
  const float* y = ydec + ((size_t)(s * 256 + b)) * 2048 + g * 512;
  float acc = 0.f;
  for (int d = 0; d < 512; ++d) acc = fmaf(y[d], w2[d * 1024 + o], acc);
  z2[idx] = acc;
}

__global__ void k_inorm2(const float* __restrict__ z2, const float* __restrict__ gamma,
                         const float* __restrict__ beta, float* __restrict__ out) {
  int o = blockIdx.y * 256 + threadIdx.x;  // 0..1023
  int b = blockIdx.x;
  float v[16], s = 0.f, s2 = 0.f;
#pragma unroll
  for (int p = 0; p < 16; ++p) {
    float xv = z2[((size_t)(b * 16 + p)) * 1024 + o];
    v[p] = xv; s += xv; s2 += xv * xv;
  }
  float mean = s * (1.f / 16.f);
  float var = s2 * (1.f / 16.f) - mean * mean;
  float sc = gamma[o] * rsqrtf(var + EPSN);
  float bt = beta[o];
#pragma unroll
  for (int p = 0; p < 16; ++p) {
    float xn = (v[p] - mean) * sc + bt;
    xn = xn >= 0.f ? xn : 0.2f * xn;
    out[((size_t)(b * 16 + p)) * 1024 + o] = xn;
  }
}

extern "C" void kernel_launch(void* const* d_in, const int* in_sizes, int n_in,
                              void* d_out, int out_size, void* d_ws, size_t ws_size,
                              hipStream_t stream) {
  (void)in_sizes; (void)n_in; (void)out_size;
  const float* x     = (const float*)d_in[0];
  const float* w1    = (const float*)d_in[1];
  const float* g1    = (const float*)d_in[2];
  const float* b1    = (const float*)d_in[3];
  const float* enc_k = (const float*)d_in[4];
  const float* enc_r = (const float*)d_in[5];
  const float* enc_b = (const float*)d_in[6];
  const float* dec_k = (const float*)d_in[7];
  const float* dec_r = (const float*)d_in[8];
  const float* dec_b = (const float*)d_in[9];
  const float* w2    = (const float*)d_in[10];
  const float* g2    = (const float*)d_in[11];
  const float* b2    = (const float*)d_in[12];
  float* out = (float*)d_out;

  if (ws_size < 64ull * 1024 * 1024) return;

  char* p = (char*)d_ws;
  auto alloc = [&](size_t bytes) { char* r = p; p += (bytes + 255) & ~(size_t)255; return r; };
  float* conv1o = (float*)alloc(4096ull * 512 * 4);     // 8 MB
  float* steps  = (float*)alloc(4ull * 256 * 2048 * 4); // 8 MB
  float* h1 = (float*)alloc(256ull * 2048 * 4);
  float* c1 = (float*)alloc(256ull * 2048 * 4);
  float* h2 = (float*)alloc(256ull * 2048 * 4);
  float* c2 = (float*)alloc(256ull * 2048 * 4);
  float* z  = (float*)alloc(256ull * 8192 * 4);         // 8 MB
  float* ydec = (float*)alloc(4ull * 256 * 2048 * 4);   // 8 MB
  float* z2 = (float*)alloc(4096ull * 1024 * 4);        // 16 MB

  hipMemsetAsync(h1, 0, 256 * 2048 * 4, stream);
  hipMemsetAsync(c1, 0, 256 * 2048 * 4, stream);
  hipMemsetAsync(h2, 0, 256 * 2048 * 4, stream);
  hipMemsetAsync(c2, 0, 256 * 2048 * 4, stream);

  k_conv1<<<8192, 256, 0, stream>>>(x, w1, conv1o);
  k_inorm1<<<dim3(256, 2), 256, 0, stream>>>(conv1o, g1, b1, steps);

  // encoder: 4 steps x 2 shared-weight layers
  for (int t = 0; t < 4; ++t) {
    k_cellz<<<8192, 256, 0, stream>>>(steps + (size_t)t * 256 * 2048, h1, enc_k, enc_r, enc_b, z);
    k_gatesf<<<2048, 256, 0, stream>>>(z, c1, h1);
    k_cellz<<<8192, 256, 0, stream>>>(h1, h2, enc_k, enc_r, enc_b, z);
    k_gatesf<<<2048, 256, 0, stream>>>(z, c2, h2);
  }
  // decoder: input steps[3], then feedback; layer-2 h state lives in ydec[s]
  for (int s = 0; s < 4; ++s) {
    const float* xin  = (s == 0) ? (steps + 3ull * 256 * 2048) : (ydec + (size_t)(s - 1) * 256 * 2048);
    const float* h2in = (s == 0) ? h2 : (ydec + (size_t)(s - 1) * 256 * 2048);
    k_cellz<<<8192, 256, 0, stream>>>(xin, h1, dec_k, dec_r, dec_b, z);
    k_gatesf<<<2048, 256, 0, stream>>>(z, c1, h1);
    k_cellz<<<8192, 256, 0, stream>>>(h1, h2in, dec_k, dec_r, dec_b, z);
    k_gatesf<<<2048, 256, 0, stream>>>(z, c2, ydec + (size_t)s * 256 * 2048);
  }

  k_conv2<<<16384, 256, 0, stream>>>(ydec, w2, z2);
  k_inorm2<<<dim3(256, 4), 256, 0, stream>>>(z2, g2, b2, out);
}

// Round 5
// 3753.067 us; speedup vs baseline: 8.0972x; 8.0972x over previous
//
#include <hip/hip_runtime.h>

#define EPSN 1e-6f

typedef __attribute__((ext_vector_type(4))) float f32x4;

__device__ __forceinline__ void async16(const void* g, void* l) {
  __builtin_amdgcn_global_load_lds(
      (const __attribute__((address_space(1))) unsigned int*)g,
      (__attribute__((address_space(3))) unsigned int*)l, 16, 0, 0);
}

// ---- transpose: out[c][r] = in[r][c], in [R][C] fp32
__global__ void kTx(const float* __restrict__ in, float* __restrict__ out, int R, int C) {
  __shared__ float t[32][33];
  int r0 = blockIdx.x * 32, c0 = blockIdx.y * 32;
  int tx = threadIdx.x, ty = threadIdx.y;  // (32,8)
#pragma unroll
  for (int j = 0; j < 4; ++j)
    t[ty + j * 8][tx] = in[(size_t)(r0 + ty + j * 8) * C + c0 + tx];
  __syncthreads();
#pragma unroll
  for (int j = 0; j < 4; ++j)
    out[(size_t)(c0 + ty + j * 8) * R + r0 + tx] = t[tx][ty + j * 8];
}

// ---- fp32 tiled GEMM: out[bz][m][n] (partial over k-chunk bz)
// A is TRANSPOSED [k][m] (k<splitK: A0/lda0 paired with B0; else A1/lda1 with B1).
// B is [k][n] with leading dim ldb. BM=256, BN=128, BK=16, 256 threads, tile 16x8.
// kchunk must not straddle splitK.
__global__ __launch_bounds__(256, 2) void kgf(
    const float* __restrict__ A0, int lda0, const float* __restrict__ A1, int lda1,
    const float* __restrict__ B0, const float* __restrict__ B1, int ldb,
    int splitK, int N, int M, int kchunk, float* __restrict__ outp) {
  __shared__ float lsA[2][16][256];
  __shared__ float lsB[2][16][128];
  const int tid = threadIdx.x, lane = tid & 63, wv = tid >> 6;
  const int n0 = blockIdx.x * 128, m0 = blockIdx.y * 256;
  const int kbase = blockIdx.z * kchunk;

  const float* A; int lda; const float* B; int koff;
  if (kbase < splitK) { A = A0; lda = lda0; B = B0; koff = kbase; }
  else                { A = A1; lda = lda1; B = B1; koff = kbase - splitK; }

  const int nt = kchunk >> 4;
  const float* asrc[4];
  const float* bsrc[2];
#pragma unroll
  for (int j = 0; j < 4; ++j)
    asrc[j] = A + (size_t)(koff + wv * 4 + j) * lda + m0 + lane * 4;
#pragma unroll
  for (int j = 0; j < 2; ++j)
    bsrc[j] = B + (size_t)(koff + wv * 4 + j * 2 + (lane >> 5)) * ldb + n0 + (lane & 31) * 4;
  const size_t astep = (size_t)16 * lda, bstep = (size_t)16 * ldb;

  auto STAGE = [&](int buf) {
#pragma unroll
    for (int j = 0; j < 4; ++j) { async16(asrc[j], &lsA[buf][wv * 4 + j][0]); asrc[j] += astep; }
#pragma unroll
    for (int j = 0; j < 2; ++j) { async16(bsrc[j], &lsB[buf][wv * 4 + j * 2][0]); bsrc[j] += bstep; }
  };

  const int mg = tid >> 4, ng = tid & 15;  // m-tile mg*16..+15, n = ng*4 & ng*4+64
  f32x4 acc[16][2];
#pragma unroll
  for (int i = 0; i < 16; ++i) {
    acc[i][0] = (f32x4){0.f, 0.f, 0.f, 0.f};
    acc[i][1] = (f32x4){0.f, 0.f, 0.f, 0.f};
  }

  STAGE(0);
  __syncthreads();
  int buf = 0;
  for (int t = 0; t < nt; ++t) {
    if (t + 1 < nt) STAGE(buf ^ 1);  // async; hidden under compute, drained by barrier
#pragma unroll
    for (int k = 0; k < 16; ++k) {
      f32x4 b0 = *(const f32x4*)&lsB[buf][k][ng * 4];
      f32x4 b1 = *(const f32x4*)&lsB[buf][k][ng * 4 + 64];
      f32x4 a[4];
#pragma unroll
      for (int i = 0; i < 4; ++i) a[i] = *(const f32x4*)&lsA[buf][k][mg * 16 + i * 4];
#pragma unroll
      for (int i = 0; i < 16; ++i) {
        float av = a[i >> 2][i & 3];
        acc[i][0] += av * b0;
        acc[i][1] += av * b1;
      }
    }
    __syncthreads();
    buf ^= 1;
  }

  float* o = outp + ((size_t)blockIdx.z * M + m0 + mg * 16) * N + n0;
#pragma unroll
  for (int i = 0; i < 16; ++i) {
    *(f32x4*)&o[(size_t)i * N + ng * 4] = acc[i][0];
    *(f32x4*)&o[(size_t)i * N + ng * 4 + 64] = acc[i][1];
  }
}

// ---- all-tanh LSTM gates; sums nparts z-partials (+optional zextra), writes hT [2048][256]
// and optionally the conv2-gathered ydecT slot for decoder step s.
__global__ void k_gates(const float* __restrict__ zpart, int nparts,
                        const float* __restrict__ zextra, const float* __restrict__ bias,
                        float* __restrict__ c, float* __restrict__ hT,
                        float* __restrict__ ydecT, int s) {
  int i = blockIdx.x * 256 + threadIdx.x;
  int b = i >> 11, u = i & 2047;
  float g4[4];
#pragma unroll
  for (int gi = 0; gi < 4; ++gi) {
    int n = u + gi * 2048;
    float v = bias[n];
    for (int p = 0; p < nparts; ++p) v += zpart[((size_t)p * 256 + b) * 8192 + n];
    if (zextra) v += zextra[(size_t)b * 8192 + n];
    g4[gi] = tanhf(v);
  }
  float cn = g4[1] * c[i] + g4[0] * g4[2];
  c[i] = cn;
  float h = g4[3] * tanhf(cn);
  hT[(size_t)u * 256 + b] = h;
  if (ydecT) ydecT[(size_t)(u & 511) * 4096 + b * 16 + ((u >> 9) << 2) + s] = h;
}

// ---- IN+lrelu after conv1 (sums 4 partials), writes stepsT [2048][1024] (m = w*256+b)
__global__ void k_inorm1(const float* __restrict__ part, const float* __restrict__ gamma,
                         const float* __restrict__ beta, float* __restrict__ stepsT) {
  int d = blockIdx.y * 256 + threadIdx.x;  // 0..511
  int b = blockIdx.x;
  float v[16], s = 0.f, s2 = 0.f;
#pragma unroll
  for (int p = 0; p < 16; ++p) {
    float xv = 0.f;
#pragma unroll
    for (int q = 0; q < 4; ++q) xv += part[((size_t)q * 4096 + b * 16 + p) * 512 + d];
    v[p] = xv; s += xv; s2 += xv * xv;
  }
  float mean = s * (1.f / 16.f);
  float var = s2 * (1.f / 16.f) - mean * mean;
  float sc = gamma[d] * rsqrtf(var + EPSN);
  float bt = beta[d];
#pragma unroll
  for (int p = 0; p < 16; ++p) {
    int hh = p >> 2, w = p & 3;
    float xn = (v[p] - mean) * sc + bt;
    xn = xn >= 0.f ? xn : 0.2f * xn;
    stepsT[(size_t)(hh * 512 + d) * 1024 + w * 256 + b] = xn;
  }
}

// ---- IN+lrelu after conv2 (sums 2 partials), writes final out [B,4,4,1024]
__global__ void k_inorm2(const float* __restrict__ part, const float* __restrict__ gamma,
                         const float* __restrict__ beta, float* __restrict__ out) {
  int o = blockIdx.y * 256 + threadIdx.x;  // 0..1023
  int b = blockIdx.x;
  float v[16], s = 0.f, s2 = 0.f;
#pragma unroll
  for (int p = 0; p < 16; ++p) {
    float xv = part[((size_t)(b * 16 + p)) * 1024 + o] +
               part[((size_t)(4096 + b * 16 + p)) * 1024 + o];
    v[p] = xv; s += xv; s2 += xv * xv;
  }
  float mean = s * (1.f / 16.f);
  float var = s2 * (1.f / 16.f) - mean * mean;
  float sc = gamma[o] * rsqrtf(var + EPSN);
  float bt = beta[o];
#pragma unroll
  for (int p = 0; p < 16; ++p) {
    float xn = (v[p] - mean) * sc + bt;
    xn = xn >= 0.f ? xn : 0.2f * xn;
    out[((size_t)(b * 16 + p)) * 1024 + o] = xn;
  }
}

extern "C" void kernel_launch(void* const* d_in, const int* in_sizes, int n_in,
                              void* d_out, int out_size, void* d_ws, size_t ws_size,
                              hipStream_t stream) {
  (void)in_sizes; (void)n_in; (void)out_size;
  const float* x     = (const float*)d_in[0];
  const float* w1    = (const float*)d_in[1];
  const float* g1    = (const float*)d_in[2];
  const float* b1    = (const float*)d_in[3];
  const float* enc_k = (const float*)d_in[4];
  const float* enc_r = (const float*)d_in[5];
  const float* enc_b = (const float*)d_in[6];
  const float* dec_k = (const float*)d_in[7];
  const float* dec_r = (const float*)d_in[8];
  const float* dec_b = (const float*)d_in[9];
  const float* w2    = (const float*)d_in[10];
  const float* g2    = (const float*)d_in[11];
  const float* b2    = (const float*)d_in[12];
  float* out = (float*)d_out;

  if (ws_size < 120ull * 1024 * 1024) return;

  char* p = (char*)d_ws;
  auto alloc = [&](size_t bytes) { char* r = p; p += (bytes + 255) & ~(size_t)255; return r; };
  float* zpart  = (float*)alloc(4ull * 256 * 8192 * 4);   // 32 MB (also conv1/conv2 partials)
  float* ZX     = (float*)alloc(4ull * 256 * 8192 * 4);   // 32 MB
  float* xT     = (float*)alloc(1024ull * 4096 * 4);      // 16 MB
  float* stepsT = (float*)alloc(2048ull * 1024 * 4);      // 8 MB
  float* ydecT  = (float*)alloc(512ull * 4096 * 4);       // 8 MB
  float* h1T    = (float*)alloc(2048ull * 256 * 4);
  float* h2T    = (float*)alloc(2048ull * 256 * 4);
  float* yT0    = (float*)alloc(2048ull * 256 * 4);
  float* yT1    = (float*)alloc(2048ull * 256 * 4);
  float* c1     = (float*)alloc(256ull * 2048 * 4);
  float* c2     = (float*)alloc(256ull * 2048 * 4);
  float* yT[2] = {yT0, yT1};

  hipMemsetAsync(h1T, 0, 2048 * 256 * 4, stream);
  hipMemsetAsync(h2T, 0, 2048 * 256 * 4, stream);
  hipMemsetAsync(c1, 0, 256 * 2048 * 4, stream);
  hipMemsetAsync(c2, 0, 256 * 2048 * 4, stream);

  // x [4096][1024] -> xT [1024][4096]
  kTx<<<dim3(128, 32), dim3(32, 8), 0, stream>>>(x, xT, 4096, 1024);

  // conv1: [4096 x 1024] @ w1[1024][512] -> zpart[4][4096][512]
  kgf<<<dim3(4, 16, 4), 256, 0, stream>>>(xT, 4096, xT, 4096, w1, w1, 512,
                                          1024, 512, 4096, 256, zpart);
  k_inorm1<<<dim3(256, 2), 256, 0, stream>>>(zpart, g1, b1, stepsT);

  // ZX = steps @ enc_k for all 4 timesteps: [1024 x 2048] @ [2048][8192]
  kgf<<<dim3(64, 4, 1), 256, 0, stream>>>(stepsT, 1024, stepsT, 1024, enc_k, enc_k, 8192,
                                          2048, 8192, 1024, 2048, ZX);

  // encoder: 4 steps x 2 shared-weight layers
  for (int t = 0; t < 4; ++t) {
    // layer1: z = ZX[t] + h1 @ enc_r
    kgf<<<dim3(64, 1, 4), 256, 0, stream>>>(h1T, 256, h1T, 256, enc_r, enc_r, 8192,
                                            2048, 8192, 256, 512, zpart);
    k_gates<<<2048, 256, 0, stream>>>(zpart, 4, ZX + (size_t)t * 256 * 8192, enc_b, c1, h1T,
                                      nullptr, 0);
    // layer2: z = h1 @ enc_k + h2 @ enc_r
    kgf<<<dim3(64, 1, 4), 256, 0, stream>>>(h1T, 256, h2T, 256, enc_k, enc_r, 8192,
                                            2048, 8192, 256, 1024, zpart);
    k_gates<<<2048, 256, 0, stream>>>(zpart, 4, nullptr, enc_b, c2, h2T, nullptr, 0);
  }
  // decoder
  for (int s = 0; s < 4; ++s) {
    const float* xin  = (s == 0) ? (stepsT + 3 * 256) : yT[(s - 1) & 1];
    int ldx           = (s == 0) ? 1024 : 256;
    const float* h2in = (s == 0) ? h2T : yT[(s - 1) & 1];
    kgf<<<dim3(64, 1, 4), 256, 0, stream>>>(xin, ldx, h1T, 256, dec_k, dec_r, 8192,
                                            2048, 8192, 256, 1024, zpart);
    k_gates<<<2048, 256, 0, stream>>>(zpart, 4, nullptr, dec_b, c1, h1T, nullptr, 0);
    kgf<<<dim3(64, 1, 4), 256, 0, stream>>>(h1T, 256, h2in, 256, dec_k, dec_r, 8192,
                                            2048, 8192, 256, 1024, zpart);
    k_gates<<<2048, 256, 0, stream>>>(zpart, 4, nullptr, dec_b, c2, yT[s & 1], ydecT, s);
  }

  // conv2: gathered y [4096 x 512] @ w2[512][1024] -> zpart[2][4096][1024]
  kgf<<<dim3(8, 16, 2), 256, 0, stream>>>(ydecT, 4096, ydecT, 4096, w2, w2, 1024,
                                          512, 1024, 4096, 256, zpart);
  k_inorm2<<<dim3(256, 4), 256, 0, stream>>>(zpart, g2, b2, out);
}

// Round 7
// 3449.558 us; speedup vs baseline: 8.8096x; 1.0880x over previous
//
#include <hip/hip_runtime.h>

#define EPSN 1e-6f

typedef __attribute__((ext_vector_type(4))) float f32x4;

__device__ __forceinline__ void async16(const void* g, void* l) {
  __builtin_amdgcn_global_load_lds(
      (const __attribute__((address_space(1))) unsigned int*)g,
      (__attribute__((address_space(3))) unsigned int*)l, 16, 0, 0);
}

// ---- transpose: out[c][r] = in[r][c], in [R][C] fp32
__global__ void kTx(const float* __restrict__ in, float* __restrict__ out, int R, int C) {
  __shared__ float t[32][33];
  int r0 = blockIdx.x * 32, c0 = blockIdx.y * 32;
  int tx = threadIdx.x, ty = threadIdx.y;  // (32,8)
#pragma unroll
  for (int j = 0; j < 4; ++j)
    t[ty + j * 8][tx] = in[(size_t)(r0 + ty + j * 8) * C + c0 + tx];
  __syncthreads();
#pragma unroll
  for (int j = 0; j < 4; ++j)
    out[(size_t)(c0 + ty + j * 8) * R + r0 + tx] = t[tx][ty + j * 8];
}

// ---- fp32 tiled GEMM: out[bz][m][n] (partial over k-chunk bz)
// A is TRANSPOSED [k][m] (k<splitK: A0/lda0 paired with B0; else A1/lda1 with B1).
// B is [k][n] leading dim ldb. BM=128, BN=128, BK=16, 256 threads, thread tile 8x8.
// kchunk must not straddle splitK.
__global__ __launch_bounds__(256, 2) void kgf(
    const float* __restrict__ A0, int lda0, const float* __restrict__ A1, int lda1,
    const float* __restrict__ B0, const float* __restrict__ B1, int ldb,
    int splitK, int N, int M, int kchunk, float* __restrict__ outp) {
  __shared__ float lsA[2][16 * 128];
  __shared__ float lsB[2][16 * 128];
  const int tid = threadIdx.x;
  const int n0 = blockIdx.x * 128, m0 = blockIdx.y * 128;
  const int kbase = blockIdx.z * kchunk;

  const float* A; int lda; const float* B; int koff;
  if (kbase < splitK) { A = A0; lda = lda0; B = B0; koff = kbase; }
  else                { A = A1; lda = lda1; B = B1; koff = kbase - splitK; }

  const int nt = kchunk >> 4;
  // staging: tile [16][128] floats = 8KB = 512 16B-chunks; 2 chunks/thread
  const float* asrc[2];
  const float* bsrc[2];
#pragma unroll
  for (int j = 0; j < 2; ++j) {
    int idx = j * 256 + tid;
    int r = idx >> 5, c4 = (idx & 31) * 4;
    asrc[j] = A + (size_t)(koff + r) * lda + m0 + c4;
    bsrc[j] = B + (size_t)(koff + r) * ldb + n0 + c4;
  }
  const size_t astep = (size_t)16 * lda, bstep = (size_t)16 * ldb;

  // global_load_lds dest = WAVE-UNIFORM base + lane*16. Chunk idx = j*256 + wv*64 + lane
  // must land at byte idx*16, so base = (j*256 + wv*64)*16; HW adds lane*16.
  // (r6 bug: base used tid*16 cancellation, dropping the wv*64 term -> waves clobbered.)
  const int wbase = (tid & ~63) * 16;  // wv*64*16 bytes
  auto STAGE = [&](int buf) {
#pragma unroll
    for (int j = 0; j < 2; ++j) {
      async16(asrc[j], (char*)&lsA[buf][0] + j * 4096 + wbase);
      async16(bsrc[j], (char*)&lsB[buf][0] + j * 4096 + wbase);
      asrc[j] += astep; bsrc[j] += bstep;
    }
  };

  const int mg = tid >> 4, ng = tid & 15;  // m rows mg*8..+7; n cols ng*4 and ng*4+64
  f32x4 acc[8][2];
#pragma unroll
  for (int i = 0; i < 8; ++i) {
    acc[i][0] = (f32x4){0.f, 0.f, 0.f, 0.f};
    acc[i][1] = (f32x4){0.f, 0.f, 0.f, 0.f};
  }

  STAGE(0);
  __syncthreads();
  int buf = 0;
  for (int t = 0; t < nt; ++t) {
    if (t + 1 < nt) STAGE(buf ^ 1);  // async into other buffer; drained by the barrier below
#pragma unroll
    for (int k = 0; k < 16; ++k) {
      f32x4 a0 = *(const f32x4*)&lsA[buf][k * 128 + mg * 8];
      f32x4 a1 = *(const f32x4*)&lsA[buf][k * 128 + mg * 8 + 4];
      f32x4 b0 = *(const f32x4*)&lsB[buf][k * 128 + ng * 4];
      f32x4 b1 = *(const f32x4*)&lsB[buf][k * 128 + ng * 4 + 64];
#pragma unroll
      for (int i = 0; i < 8; ++i) {
        float av = (i < 4) ? a0[i] : a1[i - 4];
        acc[i][0] += av * b0;
        acc[i][1] += av * b1;
      }
    }
    __syncthreads();
    buf ^= 1;
  }

  float* o = outp + ((size_t)blockIdx.z * M + m0 + mg * 8) * N + n0;
#pragma unroll
  for (int i = 0; i < 8; ++i) {
    *(f32x4*)&o[(size_t)i * N + ng * 4] = acc[i][0];
    *(f32x4*)&o[(size_t)i * N + ng * 4 + 64] = acc[i][1];
  }
}

// ---- all-tanh LSTM gates; sums nparts z-partials (+optional zextra), writes hT [2048][256]
// and optionally the conv2-gathered ydecT slot for decoder step s.
__global__ void k_gates(const float* __restrict__ zpart, int nparts,
                        const float* __restrict__ zextra, const float* __restrict__ bias,
                        float* __restrict__ c, float* __restrict__ hT,
                        float* __restrict__ ydecT, int s) {
  int i = blockIdx.x * 256 + threadIdx.x;
  int b = i >> 11, u = i & 2047;
  float g4[4];
#pragma unroll
  for (int gi = 0; gi < 4; ++gi) {
    int n = u + gi * 2048;
    float v = bias[n];
    for (int p = 0; p < nparts; ++p) v += zpart[((size_t)p * 256 + b) * 8192 + n];
    if (zextra) v += zextra[(size_t)b * 8192 + n];
    g4[gi] = tanhf(v);
  }
  float cn = g4[1] * c[i] + g4[0] * g4[2];
  c[i] = cn;
  float h = g4[3] * tanhf(cn);
  hT[(size_t)u * 256 + b] = h;
  if (ydecT) ydecT[(size_t)(u & 511) * 4096 + b * 16 + ((u >> 9) << 2) + s] = h;
}

// ---- IN+lrelu after conv1 (sums 4 partials), writes stepsT [2048][1024] (m = w*256+b)
__global__ void k_inorm1(const float* __restrict__ part, const float* __restrict__ gamma,
                         const float* __restrict__ beta, float* __restrict__ stepsT) {
  int d = blockIdx.y * 256 + threadIdx.x;  // 0..511
  int b = blockIdx.x;
  float v[16], s = 0.f, s2 = 0.f;
#pragma unroll
  for (int p = 0; p < 16; ++p) {
    float xv = 0.f;
#pragma unroll
    for (int q = 0; q < 4; ++q) xv += part[((size_t)q * 4096 + b * 16 + p) * 512 + d];
    v[p] = xv; s += xv; s2 += xv * xv;
  }
  float mean = s * (1.f / 16.f);
  float var = s2 * (1.f / 16.f) - mean * mean;
  float sc = gamma[d] * rsqrtf(var + EPSN);
  float bt = beta[d];
#pragma unroll
  for (int p = 0; p < 16; ++p) {
    int hh = p >> 2, w = p & 3;
    float xn = (v[p] - mean) * sc + bt;
    xn = xn >= 0.f ? xn : 0.2f * xn;
    stepsT[(size_t)(hh * 512 + d) * 1024 + w * 256 + b] = xn;
  }
}

// ---- IN+lrelu after conv2 (sums 2 partials), writes final out [B,4,4,1024]
__global__ void k_inorm2(const float* __restrict__ part, const float* __restrict__ gamma,
                         const float* __restrict__ beta, float* __restrict__ out) {
  int o = blockIdx.y * 256 + threadIdx.x;  // 0..1023
  int b = blockIdx.x;
  float v[16], s = 0.f, s2 = 0.f;
#pragma unroll
  for (int p = 0; p < 16; ++p) {
    float xv = part[((size_t)(b * 16 + p)) * 1024 + o] +
               part[((size_t)(4096 + b * 16 + p)) * 1024 + o];
    v[p] = xv; s += xv; s2 += xv * xv;
  }
  float mean = s * (1.f / 16.f);
  float var = s2 * (1.f / 16.f) - mean * mean;
  float sc = gamma[o] * rsqrtf(var + EPSN);
  float bt = beta[o];
#pragma unroll
  for (int p = 0; p < 16; ++p) {
    float xn = (v[p] - mean) * sc + bt;
    xn = xn >= 0.f ? xn : 0.2f * xn;
    out[((size_t)(b * 16 + p)) * 1024 + o] = xn;
  }
}

extern "C" void kernel_launch(void* const* d_in, const int* in_sizes, int n_in,
                              void* d_out, int out_size, void* d_ws, size_t ws_size,
                              hipStream_t stream) {
  (void)in_sizes; (void)n_in; (void)out_size;
  const float* x     = (const float*)d_in[0];
  const float* w1    = (const float*)d_in[1];
  const float* g1    = (const float*)d_in[2];
  const float* b1    = (const float*)d_in[3];
  const float* enc_k = (const float*)d_in[4];
  const float* enc_r = (const float*)d_in[5];
  const float* enc_b = (const float*)d_in[6];
  const float* dec_k = (const float*)d_in[7];
  const float* dec_r = (const float*)d_in[8];
  const float* dec_b = (const float*)d_in[9];
  const float* w2    = (const float*)d_in[10];
  const float* g2    = (const float*)d_in[11];
  const float* b2    = (const float*)d_in[12];
  float* out = (float*)d_out;

  if (ws_size < 120ull * 1024 * 1024) return;

  char* p = (char*)d_ws;
  auto alloc = [&](size_t bytes) { char* r = p; p += (bytes + 255) & ~(size_t)255; return r; };
  float* zpart  = (float*)alloc(4ull * 256 * 8192 * 4);   // 32 MB (also conv1/conv2 partials)
  float* ZX     = (float*)alloc(4ull * 256 * 8192 * 4);   // 32 MB
  float* xT     = (float*)alloc(1024ull * 4096 * 4);      // 16 MB
  float* stepsT = (float*)alloc(2048ull * 1024 * 4);      // 8 MB
  float* ydecT  = (float*)alloc(512ull * 4096 * 4);       // 8 MB
  float* h1T    = (float*)alloc(2048ull * 256 * 4);
  float* h2T    = (float*)alloc(2048ull * 256 * 4);
  float* yT0    = (float*)alloc(2048ull * 256 * 4);
  float* yT1    = (float*)alloc(2048ull * 256 * 4);
  float* c1     = (float*)alloc(256ull * 2048 * 4);
  float* c2     = (float*)alloc(256ull * 2048 * 4);
  float* yT[2] = {yT0, yT1};

  hipMemsetAsync(h1T, 0, 2048 * 256 * 4, stream);
  hipMemsetAsync(h2T, 0, 2048 * 256 * 4, stream);
  hipMemsetAsync(c1, 0, 256 * 2048 * 4, stream);
  hipMemsetAsync(c2, 0, 256 * 2048 * 4, stream);

  // x [4096][1024] -> xT [1024][4096]
  kTx<<<dim3(128, 32), dim3(32, 8), 0, stream>>>(x, xT, 4096, 1024);

  // conv1: [4096 x 1024] @ w1[1024][512] -> zpart[4][4096][512]   (512 blocks)
  kgf<<<dim3(4, 32, 4), 256, 0, stream>>>(xT, 4096, xT, 4096, w1, w1, 512,
                                          1024, 512, 4096, 256, zpart);
  k_inorm1<<<dim3(256, 2), 256, 0, stream>>>(zpart, g1, b1, stepsT);

  // ZX = steps @ enc_k for all 4 timesteps: [1024 x 2048] @ [2048][8192]  (512 blocks)
  kgf<<<dim3(64, 8, 1), 256, 0, stream>>>(stepsT, 1024, stepsT, 1024, enc_k, enc_k, 8192,
                                          2048, 8192, 1024, 2048, ZX);

  // encoder: 4 steps x 2 shared-weight layers  (cell GEMMs: 512 blocks each)
  for (int t = 0; t < 4; ++t) {
    // layer1: z = ZX[t] + h1 @ enc_r
    kgf<<<dim3(64, 2, 4), 256, 0, stream>>>(h1T, 256, h1T, 256, enc_r, enc_r, 8192,
                                            2048, 8192, 256, 512, zpart);
    k_gates<<<2048, 256, 0, stream>>>(zpart, 4, ZX + (size_t)t * 256 * 8192, enc_b, c1, h1T,
                                      nullptr, 0);
    // layer2: z = h1 @ enc_k + h2 @ enc_r
    kgf<<<dim3(64, 2, 4), 256, 0, stream>>>(h1T, 256, h2T, 256, enc_k, enc_r, 8192,
                                            2048, 8192, 256, 1024, zpart);
    k_gates<<<2048, 256, 0, stream>>>(zpart, 4, nullptr, enc_b, c2, h2T, nullptr, 0);
  }
  // decoder
  for (int s = 0; s < 4; ++s) {
    const float* xin  = (s == 0) ? (stepsT + 3 * 256) : yT[(s - 1) & 1];
    int ldx           = (s == 0) ? 1024 : 256;
    const float* h2in = (s == 0) ? h2T : yT[(s - 1) & 1];
    kgf<<<dim3(64, 2, 4), 256, 0, stream>>>(xin, ldx, h1T, 256, dec_k, dec_r, 8192,
                                            2048, 8192, 256, 1024, zpart);
    k_gates<<<2048, 256, 0, stream>>>(zpart, 4, nullptr, dec_b, c1, h1T, nullptr, 0);
    kgf<<<dim3(64, 2, 4), 256, 0, stream>>>(h1T, 256, h2in, 256, dec_k, dec_r, 8192,
                                            2048, 8192, 256, 1024, zpart);
    k_gates<<<2048, 256, 0, stream>>>(zpart, 4, nullptr, dec_b, c2, yT[s & 1], ydecT, s);
  }

  // conv2: gathered y [4096 x 512] @ w2[512][1024] -> zpart[2][4096][1024]  (512 blocks)
  kgf<<<dim3(8, 32, 2), 256, 0, stream>>>(ydecT, 4096, ydecT, 4096, w2, w2, 1024,
                                          512, 1024, 4096, 256, zpart);
  k_inorm2<<<dim3(256, 4), 256, 0, stream>>>(zpart, g2, b2, out);
}

// Round 8
// 1944.884 us; speedup vs baseline: 15.6253x; 1.7737x over previous
//
#include <hip/hip_runtime.h>

#define EPSN 1e-6f

typedef __attribute__((ext_vector_type(4))) float f32x4;
typedef __attribute__((ext_vector_type(8))) __bf16 bf16x8;
typedef __attribute__((ext_vector_type(4))) unsigned short us4;

__device__ __forceinline__ void async16(const void* g, void* l) {
  __builtin_amdgcn_global_load_lds(
      (const __attribute__((address_space(1))) unsigned int*)g,
      (__attribute__((address_space(3))) unsigned int*)l, 16, 0, 0);
}

// 3-level bf16 split: v ~= hi + mid + lo to ~2^-26 rel
__device__ __forceinline__ void split3(float v, unsigned short& h, unsigned short& m,
                                       unsigned short& l) {
  __bf16 a = (__bf16)v;  float fa = (float)a;
  __bf16 b = (__bf16)(v - fa); float fb = (float)b;
  __bf16 c = (__bf16)(v - fa - fb);
  h = __builtin_bit_cast(unsigned short, a);
  m = __builtin_bit_cast(unsigned short, b);
  l = __builtin_bit_cast(unsigned short, c);
}

// ---- transpose: out[c][r] = in[r][c], in [R][C] fp32 (for conv1 A-side)
__global__ void kTx(const float* __restrict__ in, float* __restrict__ out, int R, int C) {
  __shared__ float t[32][33];
  int r0 = blockIdx.x * 32, c0 = blockIdx.y * 32;
  int tx = threadIdx.x, ty = threadIdx.y;  // (32,8)
#pragma unroll
  for (int j = 0; j < 4; ++j)
    t[ty + j * 8][tx] = in[(size_t)(r0 + ty + j * 8) * C + c0 + tx];
  __syncthreads();
#pragma unroll
  for (int j = 0; j < 4; ++j)
    out[(size_t)(c0 + ty + j * 8) * R + r0 + tx] = t[tx][ty + j * 8];
}

// ==== fp32 vector GEMM (r7, proven) — used for conv1/conv2 only ====
__global__ __launch_bounds__(256, 2) void kgf(
    const float* __restrict__ A0, int lda0, const float* __restrict__ A1, int lda1,
    const float* __restrict__ B0, const float* __restrict__ B1, int ldb,
    int splitK, int N, int M, int kchunk, float* __restrict__ outp) {
  __shared__ float lsA[2][16 * 128];
  __shared__ float lsB[2][16 * 128];
  const int tid = threadIdx.x;
  const int n0 = blockIdx.x * 128, m0 = blockIdx.y * 128;
  const int kbase = blockIdx.z * kchunk;
  const float* A; int lda; const float* B; int koff;
  if (kbase < splitK) { A = A0; lda = lda0; B = B0; koff = kbase; }
  else                { A = A1; lda = lda1; B = B1; koff = kbase - splitK; }
  const int nt = kchunk >> 4;
  const float* asrc[2]; const float* bsrc[2];
#pragma unroll
  for (int j = 0; j < 2; ++j) {
    int idx = j * 256 + tid;
    int r = idx >> 5, c4 = (idx & 31) * 4;
    asrc[j] = A + (size_t)(koff + r) * lda + m0 + c4;
    bsrc[j] = B + (size_t)(koff + r) * ldb + n0 + c4;
  }
  const size_t astep = (size_t)16 * lda, bstep = (size_t)16 * ldb;
  const int wbase = (tid & ~63) * 16;
  auto STAGE = [&](int buf) {
#pragma unroll
    for (int j = 0; j < 2; ++j) {
      async16(asrc[j], (char*)&lsA[buf][0] + j * 4096 + wbase);
      async16(bsrc[j], (char*)&lsB[buf][0] + j * 4096 + wbase);
      asrc[j] += astep; bsrc[j] += bstep;
    }
  };
  const int mg = tid >> 4, ng = tid & 15;
  f32x4 acc[8][2];
#pragma unroll
  for (int i = 0; i < 8; ++i) { acc[i][0] = (f32x4){0,0,0,0}; acc[i][1] = (f32x4){0,0,0,0}; }
  STAGE(0);
  __syncthreads();
  int buf = 0;
  for (int t = 0; t < nt; ++t) {
    if (t + 1 < nt) STAGE(buf ^ 1);
#pragma unroll
    for (int k = 0; k < 16; ++k) {
      f32x4 a0 = *(const f32x4*)&lsA[buf][k * 128 + mg * 8];
      f32x4 a1 = *(const f32x4*)&lsA[buf][k * 128 + mg * 8 + 4];
      f32x4 b0 = *(const f32x4*)&lsB[buf][k * 128 + ng * 4];
      f32x4 b1 = *(const f32x4*)&lsB[buf][k * 128 + ng * 4 + 64];
#pragma unroll
      for (int i = 0; i < 8; ++i) {
        float av = (i < 4) ? a0[i] : a1[i - 4];
        acc[i][0] += av * b0; acc[i][1] += av * b1;
      }
    }
    __syncthreads();
    buf ^= 1;
  }
  float* o = outp + ((size_t)blockIdx.z * M + m0 + mg * 8) * N + n0;
#pragma unroll
  for (int i = 0; i < 8; ++i) {
    *(f32x4*)&o[(size_t)i * N + ng * 4] = acc[i][0];
    *(f32x4*)&o[(size_t)i * N + ng * 4 + 64] = acc[i][1];
  }
}

// ==== MFMA emulated-fp32 GEMM (6-term 3-way bf16 split) ====
// out[bz][m][n] partial over k-chunk bz. A: pre-split bf16 triples, [m][2048] row-major;
// k<2048 -> (Ah0,Am0,Al0)/B0, else (Ah1,..)/B1. B fp32 [k][8192]. N=8192 fixed.
// BM=BN=128, BK=32, 256 thr, 4 waves (wave tile 64x64), 16x16x32 MFMA.
__global__ __launch_bounds__(256, 2) void kgm(
    const unsigned short* __restrict__ Ah0, const unsigned short* __restrict__ Am0,
    const unsigned short* __restrict__ Al0,
    const unsigned short* __restrict__ Ah1, const unsigned short* __restrict__ Am1,
    const unsigned short* __restrict__ Al1,
    const float* __restrict__ B0, const float* __restrict__ B1,
    int Mrows, int kchunk, float* __restrict__ outp) {
  __shared__ unsigned short lsA[3 * 128 * 32];  // [split][row m][32 k], 16B-swizzled
  __shared__ unsigned short lsB[3 * 128 * 32];  // [split][row n][32 k], 16B-swizzled
  const int tid = threadIdx.x, lane = tid & 63, wv = tid >> 6;
  const int n0 = blockIdx.x * 128, m0 = blockIdx.y * 128;
  const int kbase = blockIdx.z * kchunk;

  const unsigned short *Ah, *Am, *Al; const float* B; int koff;
  if (kbase < 2048) { Ah = Ah0; Am = Am0; Al = Al0; B = B0; koff = kbase; }
  else              { Ah = Ah1; Am = Am1; Al = Al1; B = B1; koff = kbase - 2048; }
  const int nt = kchunk >> 5;

  // --- A staging (global_load_lds): 1536 16B-chunks, 6/thread. Linear dest,
  // source pre-swizzled: slot' = slot ^ ((row>>1)&3)  (read applies same XOR).
  const unsigned short* asrc[6];
  int adst[6];
#pragma unroll
  for (int j = 0; j < 6; ++j) {
    int idx = j * 256 + tid;
    int s = idx >> 9, rem = idx & 511, row = rem >> 2, slot = rem & 3;
    const unsigned short* base = (s == 0) ? Ah : ((s == 1) ? Am : Al);
    asrc[j] = base + (size_t)(m0 + row) * 2048 + koff + ((slot ^ ((row >> 1) & 3)) << 3);
    adst[j] = (j * 256 + (tid & ~63)) * 16;  // wave-uniform byte base; HW adds lane*16
  }

  // --- B staging: thread owns 4 n x 4 k; fp32 regs -> split -> swizzled ds_write_b64
  const int n0t = (tid & 31) * 4, k0g = (tid >> 5) * 4;
  const float* bptr = B + (size_t)(koff + k0g) * 8192 + n0 + n0t;
  int wboff[4];
#pragma unroll
  for (int i = 0; i < 4; ++i) {
    int n = n0t + i;
    wboff[i] = n * 32 + (((k0g >> 3) ^ ((n >> 1) & 3)) << 3) + (k0g & 4);
  }

  f32x4 bw[4];
  us4 bsh[4], bsm[4], bsl[4];
  auto LOADB = [&]() {
#pragma unroll
    for (int r = 0; r < 4; ++r) bw[r] = *(const f32x4*)(bptr + (size_t)r * 8192);
    bptr += (size_t)32 * 8192;
  };
  auto SPLITB = [&]() {
    unsigned short sh[4][4], sm[4][4], sl[4][4];
#pragma unroll
    for (int r = 0; r < 4; ++r)
#pragma unroll
      for (int i = 0; i < 4; ++i) split3(bw[r][i], sh[r][i], sm[r][i], sl[r][i]);
#pragma unroll
    for (int i = 0; i < 4; ++i) {
      bsh[i] = (us4){sh[0][i], sh[1][i], sh[2][i], sh[3][i]};
      bsm[i] = (us4){sm[0][i], sm[1][i], sm[2][i], sm[3][i]};
      bsl[i] = (us4){sl[0][i], sl[1][i], sl[2][i], sl[3][i]};
    }
  };

  const int c0 = lane >> 4, l15 = lane & 15;
  const int wm = wv >> 1, wn = wv & 1;
  f32x4 acc[4][4];
#pragma unroll
  for (int i = 0; i < 4; ++i)
#pragma unroll
    for (int j = 0; j < 4; ++j) acc[i][j] = (f32x4){0, 0, 0, 0};

  LOADB();
  SPLITB();
  for (int t = 0; t < nt; ++t) {
    __syncthreads();  // [1] prev compute done (LDS free)
#pragma unroll
    for (int j = 0; j < 6; ++j) {  // stage A tile t (drained by barrier [2])
      async16(asrc[j], (char*)lsA + adst[j]);
      asrc[j] += 32;
    }
#pragma unroll
    for (int i = 0; i < 4; ++i) {  // write B splits (loaded+split last iter)
      *(us4*)&lsB[wboff[i]] = bsh[i];
      *(us4*)&lsB[4096 + wboff[i]] = bsm[i];
      *(us4*)&lsB[8192 + wboff[i]] = bsl[i];
    }
    __syncthreads();  // [2] A staged + B written
    bool more = (t + 1 < nt);
    if (more) LOADB();  // issue next B loads; latency hidden under MFMA below
    // compute: 12+12 swizzled ds_read_b128, 96 MFMA
    bf16x8 a[4][3];
#pragma unroll
    for (int mf = 0; mf < 4; ++mf) {
      int m = wm * 64 + mf * 16 + l15;
      int ro = m * 32 + ((c0 ^ ((m >> 1) & 3)) << 3);
      a[mf][0] = *(const bf16x8*)&lsA[ro];
      a[mf][1] = *(const bf16x8*)&lsA[4096 + ro];
      a[mf][2] = *(const bf16x8*)&lsA[8192 + ro];
    }
#pragma unroll
    for (int nf = 0; nf < 4; ++nf) {
      int n = wn * 64 + nf * 16 + l15;
      int ro = n * 32 + ((c0 ^ ((n >> 1) & 3)) << 3);
      bf16x8 b0 = *(const bf16x8*)&lsB[ro];
      bf16x8 b1 = *(const bf16x8*)&lsB[4096 + ro];
      bf16x8 b2 = *(const bf16x8*)&lsB[8192 + ro];
#pragma unroll
      for (int mf = 0; mf < 4; ++mf) {
        acc[mf][nf] = __builtin_amdgcn_mfma_f32_16x16x32_bf16(a[mf][0], b0, acc[mf][nf], 0, 0, 0);
        acc[mf][nf] = __builtin_amdgcn_mfma_f32_16x16x32_bf16(a[mf][1], b0, acc[mf][nf], 0, 0, 0);
        acc[mf][nf] = __builtin_amdgcn_mfma_f32_16x16x32_bf16(a[mf][2], b0, acc[mf][nf], 0, 0, 0);
        acc[mf][nf] = __builtin_amdgcn_mfma_f32_16x16x32_bf16(a[mf][0], b1, acc[mf][nf], 0, 0, 0);
        acc[mf][nf] = __builtin_amdgcn_mfma_f32_16x16x32_bf16(a[mf][1], b1, acc[mf][nf], 0, 0, 0);
        acc[mf][nf] = __builtin_amdgcn_mfma_f32_16x16x32_bf16(a[mf][0], b2, acc[mf][nf], 0, 0, 0);
      }
    }
    if (more) SPLITB();  // VALU; overlaps MFMA tail, waits vmcnt for bw
  }

  // C/D: col = lane&15, row = (lane>>4)*4 + r  [m89-verified]
#pragma unroll
  for (int mf = 0; mf < 4; ++mf)
#pragma unroll
    for (int nf = 0; nf < 4; ++nf)
#pragma unroll
      for (int r = 0; r < 4; ++r) {
        int m = m0 + wm * 64 + mf * 16 + c0 * 4 + r;
        int n = n0 + wn * 64 + nf * 16 + l15;
        outp[((size_t)blockIdx.z * Mrows + m) * 8192 + n] = acc[mf][nf][r];
      }
}

// ---- gates: sums 4 z-partials (+opt zextra), all-tanh; writes h as bf16 split triple
// (row-major [256][2048]) + optional ydecT fp32 gather for conv2.
__global__ void k_gates(const float* __restrict__ zpart,
                        const float* __restrict__ zextra, const float* __restrict__ bias,
                        float* __restrict__ c,
                        unsigned short* __restrict__ Hh, unsigned short* __restrict__ Hm,
                        unsigned short* __restrict__ Hl,
                        float* __restrict__ ydecT, int s) {
  int i = blockIdx.x * 256 + threadIdx.x;
  int b = i >> 11, u = i & 2047;
  float g4[4];
#pragma unroll
  for (int gi = 0; gi < 4; ++gi) {
    int n = u + gi * 2048;
    float v = bias[n];
#pragma unroll
    for (int p = 0; p < 4; ++p) v += zpart[((size_t)p * 256 + b) * 8192 + n];
    if (zextra) v += zextra[(size_t)b * 8192 + n];
    g4[gi] = tanhf(v);
  }
  float cn = g4[1] * c[i] + g4[0] * g4[2];
  c[i] = cn;
  float h = g4[3] * tanhf(cn);
  unsigned short hh, hm, hl;
  split3(h, hh, hm, hl);
  Hh[i] = hh; Hm[i] = hm; Hl[i] = hl;
  if (ydecT) ydecT[(size_t)(u & 511) * 4096 + b * 16 + ((u >> 9) << 2) + s] = h;
}

// ---- IN+lrelu after conv1 (sums 4 partials), writes steps as bf16 split triple
// rows m = w*256+b, cols k = hh*512+d  ([1024][2048] row-major)
__global__ void k_inorm1(const float* __restrict__ part, const float* __restrict__ gamma,
                         const float* __restrict__ beta,
                         unsigned short* __restrict__ Sh, unsigned short* __restrict__ Sm,
                         unsigned short* __restrict__ Sl) {
  int d = blockIdx.y * 256 + threadIdx.x;  // 0..511
  int b = blockIdx.x;
  float v[16], s = 0.f, s2 = 0.f;
#pragma unroll
  for (int p = 0; p < 16; ++p) {
    float xv = 0.f;
#pragma unroll
    for (int q = 0; q < 4; ++q) xv += part[((size_t)q * 4096 + b * 16 + p) * 512 + d];
    v[p] = xv; s += xv; s2 += xv * xv;
  }
  float mean = s * (1.f / 16.f);
  float var = s2 * (1.f / 16.f) - mean * mean;
  float sc = gamma[d] * rsqrtf(var + EPSN);
  float bt = beta[d];
#pragma unroll
  for (int p = 0; p < 16; ++p) {
    int hh = p >> 2, w = p & 3;
    float xn = (v[p] - mean) * sc + bt;
    xn = xn >= 0.f ? xn : 0.2f * xn;
    size_t a = (size_t)(w * 256 + b) * 2048 + hh * 512 + d;
    unsigned short th, tm, tl;
    split3(xn, th, tm, tl);
    Sh[a] = th; Sm[a] = tm; Sl[a] = tl;
  }
}

// ---- IN+lrelu after conv2 (sums 2 partials), writes final out [B,4,4,1024]
__global__ void k_inorm2(const float* __restrict__ part, const float* __restrict__ gamma,
                         const float* __restrict__ beta, float* __restrict__ out) {
  int o = blockIdx.y * 256 + threadIdx.x;  // 0..1023
  int b = blockIdx.x;
  float v[16], s = 0.f, s2 = 0.f;
#pragma unroll
  for (int p = 0; p < 16; ++p) {
    float xv = part[((size_t)(b * 16 + p)) * 1024 + o] +
               part[((size_t)(4096 + b * 16 + p)) * 1024 + o];
    v[p] = xv; s += xv; s2 += xv * xv;
  }
  float mean = s * (1.f / 16.f);
  float var = s2 * (1.f / 16.f) - mean * mean;
  float sc = gamma[o] * rsqrtf(var + EPSN);
  float bt = beta[o];
#pragma unroll
  for (int p = 0; p < 16; ++p) {
    float xn = (v[p] - mean) * sc + bt;
    xn = xn >= 0.f ? xn : 0.2f * xn;
    out[((size_t)(b * 16 + p)) * 1024 + o] = xn;
  }
}

extern "C" void kernel_launch(void* const* d_in, const int* in_sizes, int n_in,
                              void* d_out, int out_size, void* d_ws, size_t ws_size,
                              hipStream_t stream) {
  (void)in_sizes; (void)n_in; (void)out_size;
  const float* x     = (const float*)d_in[0];
  const float* w1    = (const float*)d_in[1];
  const float* g1    = (const float*)d_in[2];
  const float* b1    = (const float*)d_in[3];
  const float* enc_k = (const float*)d_in[4];
  const float* enc_r = (const float*)d_in[5];
  const float* enc_b = (const float*)d_in[6];
  const float* dec_k = (const float*)d_in[7];
  const float* dec_r = (const float*)d_in[8];
  const float* dec_b = (const float*)d_in[9];
  const float* w2    = (const float*)d_in[10];
  const float* g2    = (const float*)d_in[11];
  const float* b2    = (const float*)d_in[12];
  float* out = (float*)d_out;

  if (ws_size < 120ull * 1024 * 1024) return;

  char* p = (char*)d_ws;
  auto alloc = [&](size_t bytes) { char* r = p; p += (bytes + 255) & ~(size_t)255; return r; };
  float* zpart = (float*)alloc(4ull * 256 * 8192 * 4);          // 32 MB (also conv partials)
  float* ZX    = (float*)alloc(4ull * 256 * 8192 * 4);          // 32 MB
  float* xT    = (float*)alloc(1024ull * 4096 * 4);             // 16 MB
  unsigned short* st3 = (unsigned short*)alloc(3ull * 1024 * 2048 * 2);  // 12 MB
  float* ydecT = (float*)alloc(512ull * 4096 * 4);              // 8 MB
  unsigned short* h1s = (unsigned short*)alloc(3ull * 256 * 2048 * 2);   // 3 MB
  unsigned short* h2s = (unsigned short*)alloc(3ull * 256 * 2048 * 2);
  unsigned short* y0s = (unsigned short*)alloc(3ull * 256 * 2048 * 2);
  unsigned short* y1s = (unsigned short*)alloc(3ull * 256 * 2048 * 2);
  float* c1 = (float*)alloc(256ull * 2048 * 4);
  float* c2 = (float*)alloc(256ull * 2048 * 4);

  const size_t SP = 1024ull * 2048;   // steps split stride (elements)
  const size_t HP = 256ull * 2048;    // h split stride
  unsigned short *sth = st3, *stm = st3 + SP, *stl = st3 + 2 * SP;
  unsigned short *h1h = h1s, *h1m = h1s + HP, *h1l = h1s + 2 * HP;
  unsigned short *h2h = h2s, *h2m = h2s + HP, *h2l = h2s + 2 * HP;
  unsigned short* ys[2] = {y0s, y1s};

  hipMemsetAsync(h1s, 0, 3 * HP * 2, stream);
  hipMemsetAsync(h2s, 0, 3 * HP * 2, stream);
  hipMemsetAsync(c1, 0, HP * 4, stream);
  hipMemsetAsync(c2, 0, HP * 4, stream);

  // conv1 (fp32 path): xT then [4096x1024]@w1 -> zpart[4][4096][512]
  kTx<<<dim3(128, 32), dim3(32, 8), 0, stream>>>(x, xT, 4096, 1024);
  kgf<<<dim3(4, 32, 4), 256, 0, stream>>>(xT, 4096, xT, 4096, w1, w1, 512,
                                          1024, 512, 4096, 256, zpart);
  k_inorm1<<<dim3(256, 2), 256, 0, stream>>>(zpart, g1, b1, sth, stm, stl);

  // ZX = steps @ enc_k for all 4 timesteps (MFMA): [1024 x 2048] @ [2048][8192]
  kgm<<<dim3(64, 8, 1), 256, 0, stream>>>(sth, stm, stl, sth, stm, stl,
                                          enc_k, enc_k, 1024, 2048, ZX);

  // encoder: 4 steps x 2 shared-weight layers
  for (int t = 0; t < 4; ++t) {
    kgm<<<dim3(64, 2, 4), 256, 0, stream>>>(h1h, h1m, h1l, h1h, h1m, h1l,
                                            enc_r, enc_r, 256, 512, zpart);
    k_gates<<<2048, 256, 0, stream>>>(zpart, ZX + (size_t)t * 256 * 8192, enc_b, c1,
                                      h1h, h1m, h1l, nullptr, 0);
    kgm<<<dim3(64, 2, 4), 256, 0, stream>>>(h1h, h1m, h1l, h2h, h2m, h2l,
                                            enc_k, enc_r, 256, 1024, zpart);
    k_gates<<<2048, 256, 0, stream>>>(zpart, nullptr, enc_b, c2,
                                      h2h, h2m, h2l, nullptr, 0);
  }
  // decoder
  for (int s = 0; s < 4; ++s) {
    const unsigned short *xh, *xm, *xl, *ph, *pm, *pl;
    if (s == 0) {
      xh = sth + 768 * 2048; xm = stm + 768 * 2048; xl = stl + 768 * 2048;
      ph = h2h; pm = h2m; pl = h2l;
    } else {
      unsigned short* pr = ys[(s - 1) & 1];
      xh = pr; xm = pr + HP; xl = pr + 2 * HP;
      ph = pr; pm = pr + HP; pl = pr + 2 * HP;
    }
    kgm<<<dim3(64, 2, 4), 256, 0, stream>>>(xh, xm, xl, h1h, h1m, h1l,
                                            dec_k, dec_r, 256, 1024, zpart);
    k_gates<<<2048, 256, 0, stream>>>(zpart, nullptr, dec_b, c1,
                                      h1h, h1m, h1l, nullptr, 0);
    kgm<<<dim3(64, 2, 4), 256, 0, stream>>>(h1h, h1m, h1l, ph, pm, pl,
                                            dec_k, dec_r, 256, 1024, zpart);
    unsigned short* cur = ys[s & 1];
    k_gates<<<2048, 256, 0, stream>>>(zpart, nullptr, dec_b, c2,
                                      cur, cur + HP, cur + 2 * HP, ydecT, s);
  }

  // conv2 (fp32 path): gathered y [4096 x 512] @ w2 -> zpart[2][4096][1024]
  kgf<<<dim3(8, 32, 2), 256, 0, stream>>>(ydecT, 4096, ydecT, 4096, w2, w2, 1024,
                                          512, 1024, 4096, 256, zpart);
  k_inorm2<<<dim3(256, 4), 256, 0, stream>>>(zpart, g2, b2, out);
}

// Round 9
// 1725.522 us; speedup vs baseline: 17.6117x; 1.1271x over previous
//
#include <hip/hip_runtime.h>

#define EPSN 1e-6f

typedef __attribute__((ext_vector_type(4))) float f32x4;
typedef __attribute__((ext_vector_type(8))) __bf16 bf16x8;
typedef __attribute__((ext_vector_type(8))) unsigned short us8;

__device__ __forceinline__ void async16(const void* g, void* l) {
  __builtin_amdgcn_global_load_lds(
      (const __attribute__((address_space(1))) unsigned int*)g,
      (__attribute__((address_space(3))) unsigned int*)l, 16, 0, 0);
}

// 3-level bf16 split: v ~= hi + mid + lo to ~2^-26 rel
__device__ __forceinline__ void split3(float v, unsigned short& h, unsigned short& m,
                                       unsigned short& l) {
  __bf16 a = (__bf16)v;  float fa = (float)a;
  __bf16 b = (__bf16)(v - fa); float fb = (float)b;
  __bf16 c = (__bf16)(v - fa - fb);
  h = __builtin_bit_cast(unsigned short, a);
  m = __builtin_bit_cast(unsigned short, b);
  l = __builtin_bit_cast(unsigned short, c);
}

// ---- transpose: out[c][r] = in[r][c], in [R][C] fp32 (for conv1 A-side)
__global__ void kTx(const float* __restrict__ in, float* __restrict__ out, int R, int C) {
  __shared__ float t[32][33];
  int r0 = blockIdx.x * 32, c0 = blockIdx.y * 32;
  int tx = threadIdx.x, ty = threadIdx.y;  // (32,8)
#pragma unroll
  for (int j = 0; j < 4; ++j)
    t[ty + j * 8][tx] = in[(size_t)(r0 + ty + j * 8) * C + c0 + tx];
  __syncthreads();
#pragma unroll
  for (int j = 0; j < 4; ++j)
    out[(size_t)(c0 + ty + j * 8) * R + r0 + tx] = t[tx][ty + j * 8];
}

// ==== fp32 vector GEMM (r7, proven) — used for conv1/conv2 only ====
__global__ __launch_bounds__(256, 2) void kgf(
    const float* __restrict__ A0, int lda0, const float* __restrict__ A1, int lda1,
    const float* __restrict__ B0, const float* __restrict__ B1, int ldb,
    int splitK, int N, int M, int kchunk, float* __restrict__ outp) {
  __shared__ float lsA[2][16 * 128];
  __shared__ float lsB[2][16 * 128];
  const int tid = threadIdx.x;
  const int n0 = blockIdx.x * 128, m0 = blockIdx.y * 128;
  const int kbase = blockIdx.z * kchunk;
  const float* A; int lda; const float* B; int koff;
  if (kbase < splitK) { A = A0; lda = lda0; B = B0; koff = kbase; }
  else                { A = A1; lda = lda1; B = B1; koff = kbase - splitK; }
  const int nt = kchunk >> 4;
  const float* asrc[2]; const float* bsrc[2];
#pragma unroll
  for (int j = 0; j < 2; ++j) {
    int idx = j * 256 + tid;
    int r = idx >> 5, c4 = (idx & 31) * 4;
    asrc[j] = A + (size_t)(koff + r) * lda + m0 + c4;
    bsrc[j] = B + (size_t)(koff + r) * ldb + n0 + c4;
  }
  const size_t astep = (size_t)16 * lda, bstep = (size_t)16 * ldb;
  const int wbase = (tid & ~63) * 16;
  auto STAGE = [&](int buf) {
#pragma unroll
    for (int j = 0; j < 2; ++j) {
      async16(asrc[j], (char*)&lsA[buf][0] + j * 4096 + wbase);
      async16(bsrc[j], (char*)&lsB[buf][0] + j * 4096 + wbase);
      asrc[j] += astep; bsrc[j] += bstep;
    }
  };
  const int mg = tid >> 4, ng = tid & 15;
  f32x4 acc[8][2];
#pragma unroll
  for (int i = 0; i < 8; ++i) { acc[i][0] = (f32x4){0,0,0,0}; acc[i][1] = (f32x4){0,0,0,0}; }
  STAGE(0);
  __syncthreads();
  int buf = 0;
  for (int t = 0; t < nt; ++t) {
    if (t + 1 < nt) STAGE(buf ^ 1);
#pragma unroll
    for (int k = 0; k < 16; ++k) {
      f32x4 a0 = *(const f32x4*)&lsA[buf][k * 128 + mg * 8];
      f32x4 a1 = *(const f32x4*)&lsA[buf][k * 128 + mg * 8 + 4];
      f32x4 b0 = *(const f32x4*)&lsB[buf][k * 128 + ng * 4];
      f32x4 b1 = *(const f32x4*)&lsB[buf][k * 128 + ng * 4 + 64];
#pragma unroll
      for (int i = 0; i < 8; ++i) {
        float av = (i < 4) ? a0[i] : a1[i - 4];
        acc[i][0] += av * b0; acc[i][1] += av * b1;
      }
    }
    __syncthreads();
    buf ^= 1;
  }
  float* o = outp + ((size_t)blockIdx.z * M + m0 + mg * 8) * N + n0;
#pragma unroll
  for (int i = 0; i < 8; ++i) {
    *(f32x4*)&o[(size_t)i * N + ng * 4] = acc[i][0];
    *(f32x4*)&o[(size_t)i * N + ng * 4 + 64] = acc[i][1];
  }
}

// ==== MFMA emulated-fp32 GEMM (6-term 3-way bf16 split) ====
// out[bz][m][n] partial over k-chunk bz. A: pre-split bf16 triples [m][2048] row-major;
// k<2048 -> (Ah0,Am0,Al0)/B0, else (Ah1,..)/B1. B fp32 [k][8192]. N=8192 fixed.
// BM=BN=128, BK=32, 256 thr, 4 waves (wave tile 64x64), 16x16x32 MFMA.
// Staging: A reg-staged (T14: load after sync2, ds_write swizzled before sync2);
// B reg-load + split3 + conflict-free ds_write_b128 into [split][kq][n][8k].
__global__ __launch_bounds__(256, 2) void kgm(
    const unsigned short* __restrict__ Ah0, const unsigned short* __restrict__ Am0,
    const unsigned short* __restrict__ Al0,
    const unsigned short* __restrict__ Ah1, const unsigned short* __restrict__ Am1,
    const unsigned short* __restrict__ Al1,
    const float* __restrict__ B0, const float* __restrict__ B1,
    int Mrows, int kchunk, float* __restrict__ outp) {
  __shared__ unsigned short lsA[3 * 128 * 32];      // [split][m][32k], slot XOR-swizzled
  __shared__ unsigned short lsB[3 * 4 * 128 * 8];   // [split][kq][n][8k], linear
  const int tid = threadIdx.x, lane = tid & 63, wv = tid >> 6;
  const int n0 = blockIdx.x * 128, m0 = blockIdx.y * 128;
  const int kbase = blockIdx.z * kchunk;

  const unsigned short *Ah, *Am, *Al; const float* B; int koff;
  if (kbase < 2048) { Ah = Ah0; Am = Am0; Al = Al0; B = B0; koff = kbase; }
  else              { Ah = Ah1; Am = Am1; Al = Al1; B = B1; koff = kbase - 2048; }
  const int nt = kchunk >> 5;

  // --- A: 1536 16B-chunks, 6/thread. chunk idx=j*256+tid -> split=idx>>9,
  // row=(idx&511)>>2, slot=idx&3. Write addr slot-XOR swizzled; read applies same XOR.
  const unsigned short* asrc[6];
  int awoff[6];  // ushort index
#pragma unroll
  for (int j = 0; j < 6; ++j) {
    int idx = j * 256 + tid;
    int s = idx >> 9, rem = idx & 511, row = rem >> 2, slot = rem & 3;
    const unsigned short* base = (s == 0) ? Ah : ((s == 1) ? Am : Al);
    asrc[j] = base + (size_t)(m0 + row) * 2048 + koff + slot * 8;
    awoff[j] = s * 4096 + row * 32 + ((slot ^ ((row >> 1) & 3)) << 3);
  }
  us8 ar[6];
  auto LOADA = [&]() {
#pragma unroll
    for (int j = 0; j < 6; ++j) { ar[j] = *(const us8*)asrc[j]; asrc[j] += 32; }
  };
  auto WRITEA = [&]() {
#pragma unroll
    for (int j = 0; j < 6; ++j) *(us8*)&lsA[awoff[j]] = ar[j];
  };

  // --- B: thread owns k rows wv*8..+7 (kq=wv), n in {lane, lane+64}.
  const float* bptr = B + (size_t)(koff + wv * 8) * 8192 + n0 + lane;
  const int bw0 = wv * 1024 + lane * 8;         // ushort idx, n=lane
  const int bw1 = wv * 1024 + (lane + 64) * 8;  // n=lane+64
  float bwa[8], bwb[8];
  us8 bs[6];  // sh_a, sm_a, sl_a, sh_b, sm_b, sl_b
  auto LOADB = [&]() {
#pragma unroll
    for (int r = 0; r < 8; ++r) {
      bwa[r] = bptr[(size_t)r * 8192];
      bwb[r] = bptr[(size_t)r * 8192 + 64];
    }
    bptr += (size_t)32 * 8192;
  };
  auto SPLITB = [&]() {
#pragma unroll
    for (int r = 0; r < 8; ++r) {
      unsigned short h, m, l;
      split3(bwa[r], h, m, l);
      bs[0][r] = h; bs[1][r] = m; bs[2][r] = l;
      split3(bwb[r], h, m, l);
      bs[3][r] = h; bs[4][r] = m; bs[5][r] = l;
    }
  };
  auto WRITEB = [&]() {
    *(us8*)&lsB[bw0] = bs[0];
    *(us8*)&lsB[4096 + bw0] = bs[1];
    *(us8*)&lsB[8192 + bw0] = bs[2];
    *(us8*)&lsB[bw1] = bs[3];
    *(us8*)&lsB[4096 + bw1] = bs[4];
    *(us8*)&lsB[8192 + bw1] = bs[5];
  };

  const int c0 = lane >> 4, l15 = lane & 15;
  const int wm = wv >> 1, wn = wv & 1;
  f32x4 acc[4][4];
#pragma unroll
  for (int i = 0; i < 4; ++i)
#pragma unroll
    for (int j = 0; j < 4; ++j) acc[i][j] = (f32x4){0, 0, 0, 0};

  LOADA();
  LOADB();
  SPLITB();
  for (int t = 0; t < nt; ++t) {
    __syncthreads();  // [1] prev compute done reading LDS
    WRITEA();         // regs staged during prev compute -> LDS (fast, conflict-free)
    WRITEB();
    __syncthreads();  // [2] tiles ready
    bool more = (t + 1 < nt);
    if (more) { LOADA(); LOADB(); }  // global latency hides under MFMA below
    bf16x8 a[4][3];
#pragma unroll
    for (int mf = 0; mf < 4; ++mf) {
      int m = wm * 64 + mf * 16 + l15;
      int ro = m * 32 + ((c0 ^ ((m >> 1) & 3)) << 3);
      a[mf][0] = *(const bf16x8*)&lsA[ro];
      a[mf][1] = *(const bf16x8*)&lsA[4096 + ro];
      a[mf][2] = *(const bf16x8*)&lsA[8192 + ro];
    }
#pragma unroll
    for (int nf = 0; nf < 4; ++nf) {
      int ro = c0 * 1024 + (wn * 64 + nf * 16 + l15) * 8;
      bf16x8 b0 = *(const bf16x8*)&lsB[ro];
      bf16x8 b1 = *(const bf16x8*)&lsB[4096 + ro];
      bf16x8 b2 = *(const bf16x8*)&lsB[8192 + ro];
#pragma unroll
      for (int mf = 0; mf < 4; ++mf) {
        acc[mf][nf] = __builtin_amdgcn_mfma_f32_16x16x32_bf16(a[mf][0], b0, acc[mf][nf], 0, 0, 0);
        acc[mf][nf] = __builtin_amdgcn_mfma_f32_16x16x32_bf16(a[mf][1], b0, acc[mf][nf], 0, 0, 0);
        acc[mf][nf] = __builtin_amdgcn_mfma_f32_16x16x32_bf16(a[mf][2], b0, acc[mf][nf], 0, 0, 0);
        acc[mf][nf] = __builtin_amdgcn_mfma_f32_16x16x32_bf16(a[mf][0], b1, acc[mf][nf], 0, 0, 0);
        acc[mf][nf] = __builtin_amdgcn_mfma_f32_16x16x32_bf16(a[mf][1], b1, acc[mf][nf], 0, 0, 0);
        acc[mf][nf] = __builtin_amdgcn_mfma_f32_16x16x32_bf16(a[mf][0], b2, acc[mf][nf], 0, 0, 0);
      }
    }
    if (more) SPLITB();  // VALU, overlaps MFMA tail; waits vmcnt for bw regs
  }

  // C/D: col = lane&15, row = (lane>>4)*4 + r  [m89-verified]
#pragma unroll
  for (int mf = 0; mf < 4; ++mf)
#pragma unroll
    for (int nf = 0; nf < 4; ++nf)
#pragma unroll
      for (int r = 0; r < 4; ++r) {
        int m = m0 + wm * 64 + mf * 16 + c0 * 4 + r;
        int n = n0 + wn * 64 + nf * 16 + l15;
        outp[((size_t)blockIdx.z * Mrows + m) * 8192 + n] = acc[mf][nf][r];
      }
}

// ---- gates: sums 4 z-partials (+opt zextra), all-tanh; writes h as bf16 split triple
// (row-major [256][2048]) + optional ydecT fp32 gather for conv2.
__global__ void k_gates(const float* __restrict__ zpart,
                        const float* __restrict__ zextra, const float* __restrict__ bias,
                        float* __restrict__ c,
                        unsigned short* __restrict__ Hh, unsigned short* __restrict__ Hm,
                        unsigned short* __restrict__ Hl,
                        float* __restrict__ ydecT, int s) {
  int i = blockIdx.x * 256 + threadIdx.x;
  int b = i >> 11, u = i & 2047;
  float g4[4];
#pragma unroll
  for (int gi = 0; gi < 4; ++gi) {
    int n = u + gi * 2048;
    float v = bias[n];
#pragma unroll
    for (int p = 0; p < 4; ++p) v += zpart[((size_t)p * 256 + b) * 8192 + n];
    if (zextra) v += zextra[(size_t)b * 8192 + n];
    g4[gi] = tanhf(v);
  }
  float cn = g4[1] * c[i] + g4[0] * g4[2];
  c[i] = cn;
  float h = g4[3] * tanhf(cn);
  unsigned short hh, hm, hl;
  split3(h, hh, hm, hl);
  Hh[i] = hh; Hm[i] = hm; Hl[i] = hl;
  if (ydecT) ydecT[(size_t)(u & 511) * 4096 + b * 16 + ((u >> 9) << 2) + s] = h;
}

// ---- IN+lrelu after conv1 (sums 4 partials), writes steps as bf16 split triple
// rows m = w*256+b, cols k = hh*512+d  ([1024][2048] row-major)
__global__ void k_inorm1(const float* __restrict__ part, const float* __restrict__ gamma,
                         const float* __restrict__ beta,
                         unsigned short* __restrict__ Sh, unsigned short* __restrict__ Sm,
                         unsigned short* __restrict__ Sl) {
  int d = blockIdx.y * 256 + threadIdx.x;  // 0..511
  int b = blockIdx.x;
  float v[16], s = 0.f, s2 = 0.f;
#pragma unroll
  for (int p = 0; p < 16; ++p) {
    float xv = 0.f;
#pragma unroll
    for (int q = 0; q < 4; ++q) xv += part[((size_t)q * 4096 + b * 16 + p) * 512 + d];
    v[p] = xv; s += xv; s2 += xv * xv;
  }
  float mean = s * (1.f / 16.f);
  float var = s2 * (1.f / 16.f) - mean * mean;
  float sc = gamma[d] * rsqrtf(var + EPSN);
  float bt = beta[d];
#pragma unroll
  for (int p = 0; p < 16; ++p) {
    int hh = p >> 2, w = p & 3;
    float xn = (v[p] - mean) * sc + bt;
    xn = xn >= 0.f ? xn : 0.2f * xn;
    size_t a = (size_t)(w * 256 + b) * 2048 + hh * 512 + d;
    unsigned short th, tm, tl;
    split3(xn, th, tm, tl);
    Sh[a] = th; Sm[a] = tm; Sl[a] = tl;
  }
}

// ---- IN+lrelu after conv2 (sums 2 partials), writes final out [B,4,4,1024]
__global__ void k_inorm2(const float* __restrict__ part, const float* __restrict__ gamma,
                         const float* __restrict__ beta, float* __restrict__ out) {
  int o = blockIdx.y * 256 + threadIdx.x;  // 0..1023
  int b = blockIdx.x;
  float v[16], s = 0.f, s2 = 0.f;
#pragma unroll
  for (int p = 0; p < 16; ++p) {
    float xv = part[((size_t)(b * 16 + p)) * 1024 + o] +
               part[((size_t)(4096 + b * 16 + p)) * 1024 + o];
    v[p] = xv; s += xv; s2 += xv * xv;
  }
  float mean = s * (1.f / 16.f);
  float var = s2 * (1.f / 16.f) - mean * mean;
  float sc = gamma[o] * rsqrtf(var + EPSN);
  float bt = beta[o];
#pragma unroll
  for (int p = 0; p < 16; ++p) {
    float xn = (v[p] - mean) * sc + bt;
    xn = xn >= 0.f ? xn : 0.2f * xn;
    out[((size_t)(b * 16 + p)) * 1024 + o] = xn;
  }
}

extern "C" void kernel_launch(void* const* d_in, const int* in_sizes, int n_in,
                              void* d_out, int out_size, void* d_ws, size_t ws_size,
                              hipStream_t stream) {
  (void)in_sizes; (void)n_in; (void)out_size;
  const float* x     = (const float*)d_in[0];
  const float* w1    = (const float*)d_in[1];
  const float* g1    = (const float*)d_in[2];
  const float* b1    = (const float*)d_in[3];
  const float* enc_k = (const float*)d_in[4];
  const float* enc_r = (const float*)d_in[5];
  const float* enc_b = (const float*)d_in[6];
  const float* dec_k = (const float*)d_in[7];
  const float* dec_r = (const float*)d_in[8];
  const float* dec_b = (const float*)d_in[9];
  const float* w2    = (const float*)d_in[10];
  const float* g2    = (const float*)d_in[11];
  const float* b2    = (const float*)d_in[12];
  float* out = (float*)d_out;

  if (ws_size < 120ull * 1024 * 1024) return;

  char* p = (char*)d_ws;
  auto alloc = [&](size_t bytes) { char* r = p; p += (bytes + 255) & ~(size_t)255; return r; };
  float* zpart = (float*)alloc(4ull * 256 * 8192 * 4);          // 32 MB (also conv partials)
  float* ZX    = (float*)alloc(4ull * 256 * 8192 * 4);          // 32 MB
  float* xT    = (float*)alloc(1024ull * 4096 * 4);             // 16 MB
  unsigned short* st3 = (unsigned short*)alloc(3ull * 1024 * 2048 * 2);  // 12 MB
  float* ydecT = (float*)alloc(512ull * 4096 * 4);              // 8 MB
  unsigned short* h1s = (unsigned short*)alloc(3ull * 256 * 2048 * 2);   // 3 MB
  unsigned short* h2s = (unsigned short*)alloc(3ull * 256 * 2048 * 2);
  unsigned short* y0s = (unsigned short*)alloc(3ull * 256 * 2048 * 2);
  unsigned short* y1s = (unsigned short*)alloc(3ull * 256 * 2048 * 2);
  float* c1 = (float*)alloc(256ull * 2048 * 4);
  float* c2 = (float*)alloc(256ull * 2048 * 4);

  const size_t SP = 1024ull * 2048;   // steps split stride (elements)
  const size_t HP = 256ull * 2048;    // h split stride
  unsigned short *sth = st3, *stm = st3 + SP, *stl = st3 + 2 * SP;
  unsigned short *h1h = h1s, *h1m = h1s + HP, *h1l = h1s + 2 * HP;
  unsigned short *h2h = h2s, *h2m = h2s + HP, *h2l = h2s + 2 * HP;
  unsigned short* ys[2] = {y0s, y1s};

  hipMemsetAsync(h1s, 0, 3 * HP * 2, stream);
  hipMemsetAsync(h2s, 0, 3 * HP * 2, stream);
  hipMemsetAsync(c1, 0, HP * 4, stream);
  hipMemsetAsync(c2, 0, HP * 4, stream);

  // conv1 (fp32 path): xT then [4096x1024]@w1 -> zpart[4][4096][512]
  kTx<<<dim3(128, 32), dim3(32, 8), 0, stream>>>(x, xT, 4096, 1024);
  kgf<<<dim3(4, 32, 4), 256, 0, stream>>>(xT, 4096, xT, 4096, w1, w1, 512,
                                          1024, 512, 4096, 256, zpart);
  k_inorm1<<<dim3(256, 2), 256, 0, stream>>>(zpart, g1, b1, sth, stm, stl);

  // ZX = steps @ enc_k for all 4 timesteps (MFMA): [1024 x 2048] @ [2048][8192]
  kgm<<<dim3(64, 8, 1), 256, 0, stream>>>(sth, stm, stl, sth, stm, stl,
                                          enc_k, enc_k, 1024, 2048, ZX);

  // encoder: 4 steps x 2 shared-weight layers
  for (int t = 0; t < 4; ++t) {
    kgm<<<dim3(64, 2, 4), 256, 0, stream>>>(h1h, h1m, h1l, h1h, h1m, h1l,
                                            enc_r, enc_r, 256, 512, zpart);
    k_gates<<<2048, 256, 0, stream>>>(zpart, ZX + (size_t)t * 256 * 8192, enc_b, c1,
                                      h1h, h1m, h1l, nullptr, 0);
    kgm<<<dim3(64, 2, 4), 256, 0, stream>>>(h1h, h1m, h1l, h2h, h2m, h2l,
                                            enc_k, enc_r, 256, 1024, zpart);
    k_gates<<<2048, 256, 0, stream>>>(zpart, nullptr, enc_b, c2,
                                      h2h, h2m, h2l, nullptr, 0);
  }
  // decoder
  for (int s = 0; s < 4; ++s) {
    const unsigned short *xh, *xm, *xl, *ph, *pm, *pl;
    if (s == 0) {
      xh = sth + 768 * 2048; xm = stm + 768 * 2048; xl = stl + 768 * 2048;
      ph = h2h; pm = h2m; pl = h2l;
    } else {
      unsigned short* pr = ys[(s - 1) & 1];
      xh = pr; xm = pr + HP; xl = pr + 2 * HP;
      ph = pr; pm = pr + HP; pl = pr + 2 * HP;
    }
    kgm<<<dim3(64, 2, 4), 256, 0, stream>>>(xh, xm, xl, h1h, h1m, h1l,
                                            dec_k, dec_r, 256, 1024, zpart);
    k_gates<<<2048, 256, 0, stream>>>(zpart, nullptr, dec_b, c1,
                                      h1h, h1m, h1l, nullptr, 0);
    kgm<<<dim3(64, 2, 4), 256, 0, stream>>>(h1h, h1m, h1l, ph, pm, pl,
                                            dec_k, dec_r, 256, 1024, zpart);
    unsigned short* cur = ys[s & 1];
    k_gates<<<2048, 256, 0, stream>>>(zpart, nullptr, dec_b, c2,
                                      cur, cur + HP, cur + 2 * HP, ydecT, s);
  }

  // conv2 (fp32 path): gathered y [4096 x 512] @ w2 -> zpart[2][4096][1024]
  kgf<<<dim3(8, 32, 2), 256, 0, stream>>>(ydecT, 4096, ydecT, 4096, w2, w2, 1024,
                                          512, 1024, 4096, 256, zpart);
  k_inorm2<<<dim3(256, 4), 256, 0, stream>>>(zpart, g2, b2, out);
}